// Round 3
// baseline (147.009 us; speedup 1.0000x reference)
//
#include <hip/hip_runtime.h>

#define BB 16384
#define DD 256
#define EE 8
#define HH 128
#define RBLK 512          // routing blocks, 32 rows each
#define TBLK 96           // transpose blocks
#define CS_S 136          // 128 + 8 bf16 pad

typedef __attribute__((ext_vector_type(8))) short short8;   // 8 bf16 = 4 VGPRs
typedef __attribute__((ext_vector_type(4))) float f32x4;

// fp32 -> bf16 round-to-nearest-even (values are finite; no NaN care needed)
__device__ __forceinline__ ushort f2bf(float f){
    const unsigned u = __float_as_uint(f);
    return (ushort)((u + 0x7fffu + ((u >> 16) & 1u)) >> 16);
}
__device__ __forceinline__ float bf2f(ushort s){
    return __uint_as_float(((unsigned)s) << 16);
}
__device__ __forceinline__ float fast_tanh(float v){
    v = fminf(fmaxf(v, -15.0f), 15.0f);
    const float a = __expf(2.0f * v);
    return (a - 1.0f) / (a + 1.0f);
}

// ---------------------------------------------------------------------------
// D1 shared-memory overlay: transpose blocks use tile; routing blocks use rt.
struct RT {
    float WgT[EE][DD];   // 8 KB
    int   le[64];        // slot s: e0 at [s], e1 at [32+s]
    float lw[64];
    int   loff[64];
    int   lcount[EE];
};
union ShU { float tile[64 * 68]; RT rt; };   // 17.4 KB

// ---------------------------------------------------------------------------
// Weight transpose body: W1 [e][k=256][h=128] fp32 -> W1t [e][h][k] bf16;
// Wp likewise. b in [0,96): 64 W1 tiles + 32 Wp tiles of 64x64.
__device__ __forceinline__ void transpose_body(int b, int t,
    const float* __restrict__ W1, const float* __restrict__ Wp,
    ushort* __restrict__ W1t, ushort* __restrict__ Wpt, float* tile)
{
    const float* src; ushort* dst; int K;
    int k0, h0;
    if (b < 64){                                    // W1: 8e x 4kt x 2ht
        const int e = b >> 3, kt = (b >> 1) & 3, ht = b & 1;
        src = W1 + (size_t)e * DD * HH;  dst = W1t + (size_t)e * HH * DD;
        K = DD; k0 = kt * 64; h0 = ht * 64;
    } else {                                        // Wp: 8e x 2kt x 2ht
        b -= 64;
        const int e = b >> 2, kt = (b >> 1) & 1, ht = b & 1;
        src = Wp + (size_t)e * HH * HH;  dst = Wpt + (size_t)e * HH * HH;
        K = HH; k0 = kt * 64; h0 = ht * 64;
    }
    #pragma unroll
    for (int j = 0; j < 4; j++){
        const int idx = t + 256 * j;               // 1024 float4 = 64x64
        const int kk = idx >> 4, hh = (idx & 15) * 4;
        const float4 v = *(const float4*)(src + (size_t)(k0 + kk) * HH + h0 + hh);
        *(float4*)&tile[kk * 68 + hh] = v;
    }
    __syncthreads();
    #pragma unroll
    for (int j = 0; j < 4; j++){
        const int idx = t + 256 * j;
        const int hh = idx >> 4, kk = (idx & 15) * 4;
        ushort4 o;
        o.x = f2bf(tile[(kk + 0) * 68 + hh]);
        o.y = f2bf(tile[(kk + 1) * 68 + hh]);
        o.z = f2bf(tile[(kk + 2) * 68 + hh]);
        o.w = f2bf(tile[(kk + 3) * 68 + hh]);
        *(ushort4*)&dst[(size_t)(h0 + hh) * K + k0 + kk] = o;
    }
}

// ---------------------------------------------------------------------------
// D1: transpose (blocks 0..95) || routing (blocks 96..607). No global RMW,
// no inter-block ordering: routing block rb writes ONLY hist[e][rb] and its
// private segments seg_rid/seg_wgt[(e*RBLK+rb)*32 + slot]. Gating math is
// bit-identical to the verified kernel (fp32, same order, same top-2 logic).
__global__ __launch_bounds__(256) void prep_kernel(
    const float* __restrict__ x, const float* __restrict__ Wg,
    const float* __restrict__ W1, const float* __restrict__ Wp,
    ushort* __restrict__ W1t, ushort* __restrict__ Wpt,
    ushort* __restrict__ xbf, float* __restrict__ out,
    int* __restrict__ hist, int* __restrict__ seg_rid, float* __restrict__ seg_wgt)
{
    __shared__ ShU sh;
    const int t = threadIdx.x;
    if (blockIdx.x < TBLK){
        transpose_body(blockIdx.x, t, W1, Wp, W1t, Wpt, sh.tile);
        return;
    }
    RT* rt = &sh.rt;
    const int rb = blockIdx.x - TBLK;
    const int rowBase = rb * 32;
    if (t < 32) out[rowBase + t] = 0.0f;
    {
        const float4* g = (const float4*)(Wg + t * EE);
        const float4 a = g[0], b = g[1];
        rt->WgT[0][t] = a.x; rt->WgT[1][t] = a.y; rt->WgT[2][t] = a.z; rt->WgT[3][t] = a.w;
        rt->WgT[4][t] = b.x; rt->WgT[5][t] = b.y; rt->WgT[6][t] = b.z; rt->WgT[7][t] = b.w;
    }
    if (t < EE) rt->lcount[t] = 0;
    __syncthreads();

    const int lane = t & 63;
    const int wid  = t >> 6;

    for (int it = 0; it < 8; it++){
        const int slot = wid * 8 + it;
        const int row  = rowBase + slot;
        const float4 xv = *(const float4*)(x + row * DD + lane * 4);
        {   // bf16 copy of x for the expert kernel's A-fragment gather
            ushort4 o;
            o.x = f2bf(xv.x); o.y = f2bf(xv.y); o.z = f2bf(xv.z); o.w = f2bf(xv.w);
            *(ushort4*)&xbf[(size_t)row * DD + lane * 4] = o;
        }
        float p[EE];
        #pragma unroll
        for (int e = 0; e < EE; e++){
            const float4 ww = *(const float4*)&rt->WgT[e][lane * 4];
            p[e] = xv.x * ww.x + xv.y * ww.y + xv.z * ww.z + xv.w * ww.w;
        }
        #pragma unroll
        for (int off = 32; off >= 1; off >>= 1){
            #pragma unroll
            for (int e = 0; e < EE; e++) p[e] += __shfl_down(p[e], off, 64);
        }
        if (lane == 0){
            int e0 = 0; float l0 = p[0];
            #pragma unroll
            for (int e = 1; e < EE; e++){ if (p[e] > l0){ l0 = p[e]; e0 = e; } }
            int e1 = -1; float l1 = -3.0e38f;
            #pragma unroll
            for (int e = 0; e < EE; e++){ if (e != e0 && p[e] > l1){ l1 = p[e]; e1 = e; } }
            const float tt  = __expf(l1 - l0);            // <= 1
            const float inv = 1.0f / (1.0f + tt);
            rt->le[slot]      = e0;  rt->lw[slot]      = inv;
            rt->le[32 + slot] = e1;  rt->lw[32 + slot] = tt * inv;
        }
    }
    __syncthreads();
    if (t < 64) rt->loff[t] = atomicAdd(&rt->lcount[rt->le[t]], 1);   // LDS only
    __syncthreads();
    if (t < EE) hist[t * RBLK + rb] = rt->lcount[t];
    if (t < 64){
        const int e = rt->le[t];
        const int o = (e * RBLK + rb) * 32 + rt->loff[t];             // <=32/(rb,e)
        seg_rid[o] = rowBase + (t & 31);
        seg_wgt[o] = rt->lw[t];
    }
}

// ---------------------------------------------------------------------------
// D2: expert chunks. Each block (c, me) self-locates its 64 rows via a
// wave-0 exclusive scan of hist[me][*] + per-lane binary search (replaces
// the old global atomic compaction -- no counts array, no zeroing needed).
// Expert math identical to the verified kernel; A-fragments gather straight
// from xbf (bit-identical bf16 values the Xs LDS staging used to hold).
__global__ __launch_bounds__(256, 3) void expert_kernel(
    const ushort* __restrict__ xbf,
    const ushort* __restrict__ W1t, const float* __restrict__ b1,
    const ushort* __restrict__ Wpt, const float* __restrict__ bp,
    const float* __restrict__ mix_logit,
    const float* __restrict__ Wo, const float* __restrict__ bo,
    const int* __restrict__ hist, const int* __restrict__ seg_rid,
    const float* __restrict__ seg_wgt, float* __restrict__ out)
{
    __shared__ ushort coreS[64 * CS_S];   // 17.4 KB
    __shared__ int    Ps[RBLK + 1];       // exclusive prefix of hist[me][*]
    __shared__ int    rid_s[64];
    __shared__ float  w_s[64];

    const int me = blockIdx.y;
    const int t  = threadIdx.x;

    // wave-0 scan: lane l handles hist[me][l*8 .. l*8+8)
    if (t < 64){
        int h[8], incl[8];
        int s = 0;
        #pragma unroll
        for (int i = 0; i < 8; i++){ h[i] = hist[me * RBLK + t * 8 + i]; s += h[i]; incl[i] = s; }
        int run = s;
        #pragma unroll
        for (int off = 1; off < 64; off <<= 1){
            const int n = __shfl_up(run, off, 64);
            if (t >= off) run += n;
        }
        const int excl = run - s;                       // exclusive lane prefix
        #pragma unroll
        for (int i = 0; i < 8; i++) Ps[t * 8 + i] = excl + incl[i] - h[i];
        if (t == 63) Ps[RBLK] = excl + s;               // total count
    }
    __syncthreads();
    const int cnt   = Ps[RBLK];
    const int start = blockIdx.x * 64;
    if (start >= cnt) return;

    if (t < 64){
        const int s = start + t;
        if (s < cnt){
            int lo = 0, hi = RBLK - 1;                  // largest b: Ps[b] <= s
            while (lo < hi){
                const int mid = (lo + hi + 1) >> 1;
                if (Ps[mid] <= s) lo = mid; else hi = mid - 1;
            }
            const int o = (me * RBLK + lo) * 32 + (s - Ps[lo]);
            rid_s[t] = seg_rid[o];
            w_s[t]   = seg_wgt[o];
        } else { rid_s[t] = 0; w_s[t] = 0.0f; }
    }
    __syncthreads();

    const int lane = t & 63;
    const int w    = t >> 6;
    const int m16  = lane & 15;
    const int q    = lane >> 4;
    const int r0   = 32 * (w >> 1);
    const int c0   = 64 * (w & 1);

    // per-lane A-row pointers (rows r0+m16 and r0+16+m16)
    const ushort* xrA = xbf + (size_t)rid_s[r0 + m16]      * DD;
    const ushort* xrB = xbf + (size_t)rid_s[r0 + 16 + m16] * DD;

    // ---- GEMM1: core_pre = X @ W1 + b1 ----
    f32x4 acc[2][4];
    #pragma unroll
    for (int ct = 0; ct < 4; ct++){
        const float bj = b1[me * HH + c0 + ct * 16 + m16];
        #pragma unroll
        for (int rt = 0; rt < 2; rt++) acc[rt][ct] = (f32x4){bj, bj, bj, bj};
    }
    const ushort* W1te = W1t + (size_t)me * HH * DD;
    #pragma unroll
    for (int ks = 0; ks < 8; ks++){
        short8 af[2], bfr[4];
        af[0] = *(const short8*)&xrA[ks * 32 + q * 8];
        af[1] = *(const short8*)&xrB[ks * 32 + q * 8];
        #pragma unroll
        for (int ct = 0; ct < 4; ct++)
            bfr[ct] = *(const short8*)&W1te[(size_t)(c0 + ct * 16 + m16) * DD + ks * 32 + q * 8];
        #pragma unroll
        for (int rt = 0; rt < 2; rt++)
            #pragma unroll
            for (int ct = 0; ct < 4; ct++)
                acc[rt][ct] = __builtin_amdgcn_mfma_f32_16x16x32_bf16(af[rt], bfr[ct], acc[rt][ct], 0, 0, 0);
    }

    // relu -> bf16 core into LDS (A-operand source for GEMM2 + epilogue reuse)
    #pragma unroll
    for (int rt = 0; rt < 2; rt++)
        #pragma unroll
        for (int ct = 0; ct < 4; ct++)
            #pragma unroll
            for (int j = 0; j < 4; j++){
                const int row = r0 + rt * 16 + q * 4 + j;
                const int col = c0 + ct * 16 + m16;
                coreS[row * CS_S + col] = f2bf(fmaxf(acc[rt][ct][j], 0.0f));
            }
    __syncthreads();

    // ---- GEMM2: plast_pre = core @ Wp + bp ----
    #pragma unroll
    for (int ct = 0; ct < 4; ct++){
        const float bj = bp[me * HH + c0 + ct * 16 + m16];
        #pragma unroll
        for (int rt = 0; rt < 2; rt++) acc[rt][ct] = (f32x4){bj, bj, bj, bj};
    }
    const ushort* Wpte = Wpt + (size_t)me * HH * HH;
    #pragma unroll
    for (int ks = 0; ks < 4; ks++){
        const int k0 = ks * 32;
        short8 af[2], bfr[4];
        #pragma unroll
        for (int rt = 0; rt < 2; rt++)
            af[rt] = *(const short8*)&coreS[(r0 + rt * 16 + m16) * CS_S + k0 + q * 8];
        #pragma unroll
        for (int ct = 0; ct < 4; ct++)
            bfr[ct] = *(const short8*)&Wpte[(size_t)(c0 + ct * 16 + m16) * HH + k0 + q * 8];
        #pragma unroll
        for (int rt = 0; rt < 2; rt++)
            #pragma unroll
            for (int ct = 0; ct < 4; ct++)
                acc[rt][ct] = __builtin_amdgcn_mfma_f32_16x16x32_bf16(af[rt], bfr[ct], acc[rt][ct], 0, 0, 0);
    }

    // ---- epilogue: out_row = sum_h [core*(1-m) + m*tanh(plast)] * Wo + bo ----
    const float mv  = 1.0f / (1.0f + __expf(-mix_logit[me]));
    const float om  = 1.0f - mv;
    const float bov = bo[me];
    float wo[4];
    #pragma unroll
    for (int ct = 0; ct < 4; ct++) wo[ct] = Wo[me * HH + c0 + ct * 16 + m16];

    float red[2][4];
    #pragma unroll
    for (int rt = 0; rt < 2; rt++)
        #pragma unroll
        for (int j = 0; j < 4; j++){
            float s = 0.0f;
            const int row = r0 + rt * 16 + q * 4 + j;
            #pragma unroll
            for (int ct = 0; ct < 4; ct++){
                const int col = c0 + ct * 16 + m16;
                const float pl = fast_tanh(acc[rt][ct][j]);
                const float cv = bf2f(coreS[row * CS_S + col]);
                s = fmaf(om * cv + mv * pl, wo[ct], s);
            }
            red[rt][j] = s;
        }
    #pragma unroll
    for (int off = 8; off >= 1; off >>= 1)
        #pragma unroll
        for (int rt = 0; rt < 2; rt++)
            #pragma unroll
            for (int j = 0; j < 4; j++)
                red[rt][j] += __shfl_xor(red[rt][j], off, 64);   // reduce over m16

    if (m16 == 0){
        const float bb = (c0 == 0) ? bov : 0.0f;   // bias from one col-half only
        #pragma unroll
        for (int rt = 0; rt < 2; rt++)
            #pragma unroll
            for (int j = 0; j < 4; j++){
                const int row = r0 + rt * 16 + q * 4 + j;
                const float ww = w_s[row];
                if (ww != 0.0f) atomicAdd(&out[rid_s[row]], (red[rt][j] + bb) * ww);
            }
    }
}

// ---------------------------------------------------------------------------
extern "C" void kernel_launch(void* const* d_in, const int* in_sizes, int n_in,
                              void* d_out, int out_size, void* d_ws, size_t ws_size,
                              hipStream_t stream) {
    (void)in_sizes; (void)n_in; (void)out_size; (void)ws_size;
    const float* x   = (const float*)d_in[0];
    const float* Wg  = (const float*)d_in[1];
    const float* W1  = (const float*)d_in[2];
    const float* b1  = (const float*)d_in[3];
    const float* Wp  = (const float*)d_in[4];
    const float* bp  = (const float*)d_in[5];
    const float* ml  = (const float*)d_in[6];
    const float* Wo  = (const float*)d_in[7];
    const float* bo  = (const float*)d_in[8];
    float* out = (float*)d_out;

    // ws layout (all 1KB-aligned):
    //   hist    E*RBLK*4        = 16 KB
    //   seg_rid E*RBLK*32*4     = 512 KB
    //   seg_wgt E*RBLK*32*4     = 512 KB
    //   W1t     E*HH*DD*2       = 512 KB
    //   Wpt     E*HH*HH*2       = 256 KB
    //   xbf     BB*DD*2         = 8 MB
    char* ws = (char*)d_ws;
    int*    hist    = (int*)ws;
    int*    seg_rid = (int*)(ws + (16 << 10));
    float*  seg_wgt = (float*)(ws + (16 << 10) + (512 << 10));
    ushort* W1t     = (ushort*)(ws + (16 << 10) + 2 * (512 << 10));
    ushort* Wpt     = W1t + (size_t)EE * HH * DD;
    ushort* xbf     = Wpt + (size_t)EE * HH * HH;

    // 2 dispatches, no memsets, no grid-wide sync.
    prep_kernel<<<TBLK + RBLK, 256, 0, stream>>>(
        x, Wg, W1, Wp, W1t, Wpt, xbf, out, hist, seg_rid, seg_wgt);
    expert_kernel<<<dim3(BB / 64, EE), 256, 0, stream>>>(
        xbf, W1t, b1, Wpt, bp, ml, Wo, bo, hist, seg_rid, seg_wgt, out);
}

// Round 4
// 136.577 us; speedup vs baseline: 1.0764x; 1.0764x over previous
//
#include <hip/hip_runtime.h>

#define BB 16384
#define DD 256
#define EE 8
#define HH 128
#define RBLK 512          // routing blocks, 32 rows each
#define TBLK 96           // transpose blocks
#define CS_S 136          // 128 + 8 bf16 pad

typedef __attribute__((ext_vector_type(8))) short short8;   // 8 bf16 = 4 VGPRs
typedef __attribute__((ext_vector_type(4))) float f32x4;

// fp32 -> bf16 round-to-nearest-even (values are finite; no NaN care needed)
__device__ __forceinline__ ushort f2bf(float f){
    const unsigned u = __float_as_uint(f);
    return (ushort)((u + 0x7fffu + ((u >> 16) & 1u)) >> 16);
}
__device__ __forceinline__ float bf2f(ushort s){
    return __uint_as_float(((unsigned)s) << 16);
}
__device__ __forceinline__ float fast_tanh(float v){
    v = fminf(fmaxf(v, -15.0f), 15.0f);
    const float a = __expf(2.0f * v);
    return (a - 1.0f) / (a + 1.0f);
}
// async global->LDS, 16B per lane; LDS dest is wave-uniform base + lane*16
__device__ __forceinline__ void gload_lds16(const void* g, void* l){
    __builtin_amdgcn_global_load_lds(
        (const __attribute__((address_space(1))) unsigned*)g,
        (__attribute__((address_space(3))) unsigned*)l, 16, 0, 0);
}

// ---------------------------------------------------------------------------
// D1 shared-memory overlay: transpose blocks use tile; routing blocks use rt.
struct RT {
    float WgT[EE][DD];   // 8 KB
    int   le[64];        // slot s: e0 at [s], e1 at [32+s]
    float lw[64];
};
union ShU { float tile[64 * 68]; RT rt; };   // 17.4 KB

// ---------------------------------------------------------------------------
// Weight transpose body: W1 [e][k=256][h=128] fp32 -> W1t [e][h][k] bf16;
// Wp likewise. b in [0,96): 64 W1 tiles + 32 Wp tiles of 64x64.
__device__ __forceinline__ void transpose_body(int b, int t,
    const float* __restrict__ W1, const float* __restrict__ Wp,
    ushort* __restrict__ W1t, ushort* __restrict__ Wpt, float* tile)
{
    const float* src; ushort* dst; int K;
    int k0, h0;
    if (b < 64){                                    // W1: 8e x 4kt x 2ht
        const int e = b >> 3, kt = (b >> 1) & 3, ht = b & 1;
        src = W1 + (size_t)e * DD * HH;  dst = W1t + (size_t)e * HH * DD;
        K = DD; k0 = kt * 64; h0 = ht * 64;
    } else {                                        // Wp: 8e x 2kt x 2ht
        b -= 64;
        const int e = b >> 2, kt = (b >> 1) & 1, ht = b & 1;
        src = Wp + (size_t)e * HH * HH;  dst = Wpt + (size_t)e * HH * HH;
        K = HH; k0 = kt * 64; h0 = ht * 64;
    }
    #pragma unroll
    for (int j = 0; j < 4; j++){
        const int idx = t + 256 * j;               // 1024 float4 = 64x64
        const int kk = idx >> 4, hh = (idx & 15) * 4;
        const float4 v = *(const float4*)(src + (size_t)(k0 + kk) * HH + h0 + hh);
        *(float4*)&tile[kk * 68 + hh] = v;
    }
    __syncthreads();
    #pragma unroll
    for (int j = 0; j < 4; j++){
        const int idx = t + 256 * j;
        const int hh = idx >> 4, kk = (idx & 15) * 4;
        ushort4 o;
        o.x = f2bf(tile[(kk + 0) * 68 + hh]);
        o.y = f2bf(tile[(kk + 1) * 68 + hh]);
        o.z = f2bf(tile[(kk + 2) * 68 + hh]);
        o.w = f2bf(tile[(kk + 3) * 68 + hh]);
        *(ushort4*)&dst[(size_t)(h0 + hh) * K + k0 + kk] = o;
    }
}

// ---------------------------------------------------------------------------
// D1: transpose (blocks 0..95) || routing (blocks 96..607).
// Routing writes ONLY per-row route info (e0,e1,w0,w1) -- no histogram, no
// compaction, no atomics, no out zeroing. Gating math bit-identical to the
// verified kernel (fp32, same summation order, same top-2 logic).
__global__ __launch_bounds__(256) void prep_kernel(
    const float* __restrict__ x, const float* __restrict__ Wg,
    const float* __restrict__ W1, const float* __restrict__ Wp,
    ushort* __restrict__ W1t, ushort* __restrict__ Wpt,
    ushort* __restrict__ xbf, float4* __restrict__ route)
{
    __shared__ ShU sh;
    const int t = threadIdx.x;
    if (blockIdx.x < TBLK){
        transpose_body(blockIdx.x, t, W1, Wp, W1t, Wpt, sh.tile);
        return;
    }
    RT* rt = &sh.rt;
    const int rb = blockIdx.x - TBLK;
    const int rowBase = rb * 32;
    {
        const float4* g = (const float4*)(Wg + t * EE);
        const float4 a = g[0], b = g[1];
        rt->WgT[0][t] = a.x; rt->WgT[1][t] = a.y; rt->WgT[2][t] = a.z; rt->WgT[3][t] = a.w;
        rt->WgT[4][t] = b.x; rt->WgT[5][t] = b.y; rt->WgT[6][t] = b.z; rt->WgT[7][t] = b.w;
    }
    __syncthreads();

    const int lane = t & 63;
    const int wid  = t >> 6;

    for (int it = 0; it < 8; it++){
        const int slot = wid * 8 + it;
        const int row  = rowBase + slot;
        const float4 xv = *(const float4*)(x + row * DD + lane * 4);
        {   // bf16 copy of x for the dense kernel's A-staging
            ushort4 o;
            o.x = f2bf(xv.x); o.y = f2bf(xv.y); o.z = f2bf(xv.z); o.w = f2bf(xv.w);
            *(ushort4*)&xbf[(size_t)row * DD + lane * 4] = o;
        }
        float p[EE];
        #pragma unroll
        for (int e = 0; e < EE; e++){
            const float4 ww = *(const float4*)&rt->WgT[e][lane * 4];
            p[e] = xv.x * ww.x + xv.y * ww.y + xv.z * ww.z + xv.w * ww.w;
        }
        #pragma unroll
        for (int off = 32; off >= 1; off >>= 1){
            #pragma unroll
            for (int e = 0; e < EE; e++) p[e] += __shfl_down(p[e], off, 64);
        }
        if (lane == 0){
            int e0 = 0; float l0 = p[0];
            #pragma unroll
            for (int e = 1; e < EE; e++){ if (p[e] > l0){ l0 = p[e]; e0 = e; } }
            int e1 = -1; float l1 = -3.0e38f;
            #pragma unroll
            for (int e = 0; e < EE; e++){ if (e != e0 && p[e] > l1){ l1 = p[e]; e1 = e; } }
            const float tt  = __expf(l1 - l0);            // <= 1
            const float inv = 1.0f / (1.0f + tt);
            rt->le[slot]      = e0;  rt->lw[slot]      = inv;
            rt->le[32 + slot] = e1;  rt->lw[32 + slot] = tt * inv;
        }
    }
    __syncthreads();
    if (t < 32){
        route[rowBase + t] = make_float4(__int_as_float(rt->le[t]),
                                         __int_as_float(rt->le[32 + t]),
                                         rt->lw[t], rt->lw[32 + t]);
    }
}

// ---------------------------------------------------------------------------
// D2: DENSE expert kernel. 256 blocks x 512 threads, 64 rows/block, natural
// row order (no gather, no atomics, no imbalance). Every block computes all
// 8 experts; per-row top-2 weights select contributions (w=0 exactly for
// non-picked experts -> bit-identical to computing only the picks).
//
// Wave layout: 8 waves = 4 expert-groups x 2 col-halves.
//   g = w>>1 owns experts {2g, 2g+1}; c0 = 64*(w&1); all 64 rows per wave
//   (4 row-tiles of 16). Block-aggregate B-traffic = W1t+Wpt exactly once
//   (768 KB from L2, no inter-wave duplication).
// Per sub-iteration (sub = 0,1), uniform across waves:
//   wES[g] <- per-row weight for e=2g+sub;  GEMM1 -> relu -> coreS[g];
//   sync;  GEMM2 + epilogue partial (reads coreS[g], wES[g]);  sync.
// Final: shfl-reduce over m16, redS[8][64] cross-wave sum, single store.
__global__ __launch_bounds__(512, 1) void dense_kernel(
    const ushort* __restrict__ xbf,
    const ushort* __restrict__ W1t, const float* __restrict__ b1,
    const ushort* __restrict__ Wpt, const float* __restrict__ bp,
    const float* __restrict__ mix_logit,
    const float* __restrict__ Wo, const float* __restrict__ bo,
    const float4* __restrict__ route, float* __restrict__ out)
{
    __shared__ ushort Xs[64 * DD];            // 32 KB, XOR-swizzled content
    __shared__ ushort coreS[4][64 * CS_S];    // 68 KB (one per expert-group)
    __shared__ float4 routeS[64];             // 1 KB
    __shared__ float  wES[4][64];             // 1 KB
    __shared__ float  redS[8][64];            // 2 KB
    __shared__ float  mvS[EE], boS[EE];

    const int t = threadIdx.x;
    const int rowBase = blockIdx.x * 64;
    const int lane = t & 63;
    const int w    = t >> 6;

    if (t < 64) routeS[t] = route[rowBase + t];
    if (t < EE){ mvS[t] = 1.0f / (1.0f + __expf(-mix_logit[t])); boS[t] = bo[t]; }

    // stage 64 rows of xbf: 8 waves x 4 instrs x 1KB (2 rows each)
    {
        const int rsub = lane >> 5;          // row within the pair
        const int c    = lane & 31;          // 16B chunk within row
        #pragma unroll
        for (int i = 0; i < 4; i++){
            const int row = w * 8 + i * 2 + rsub;
            const int sc  = c ^ (row & 7);   // pre-swizzled source chunk
            const ushort* gp = xbf + (size_t)(rowBase + row) * DD + sc * 8;
            gload_lds16(gp, &Xs[(w * 8 + i * 2) * DD]);
        }
    }
    asm volatile("s_waitcnt vmcnt(0)" ::: "memory");
    __syncthreads();

    const int m16  = lane & 15;
    const int q    = lane >> 4;
    const int g    = w >> 1;                 // expert-group
    const int half = w & 1;
    const int c0   = 64 * half;
    const int swz  = m16 & 7;                // == row&7 for all A-rows this lane reads
    ushort* coreSg = coreS[g];

    float red[4][4];
    #pragma unroll
    for (int rt = 0; rt < 4; rt++)
        #pragma unroll
        for (int j = 0; j < 4; j++) red[rt][j] = 0.0f;

    #pragma unroll 1
    for (int sub = 0; sub < 2; sub++){
        const int e = 2 * g + sub;

        // per-row weight for this expert (0 if not in the row's top-2)
        if ((t & 127) < 64){
            const int row = t & 127;
            const float4 rv = routeS[row];
            const int e0 = __float_as_int(rv.x);
            const int e1 = __float_as_int(rv.y);
            wES[g][row] = (e == e0) ? rv.z : ((e == e1) ? rv.w : 0.0f);
        }

        // ---- GEMM1: core_pre = X @ W1[e] + b1[e] ----
        f32x4 acc[4][4];
        #pragma unroll
        for (int ct = 0; ct < 4; ct++){
            const float bj = b1[e * HH + c0 + ct * 16 + m16];
            #pragma unroll
            for (int rt = 0; rt < 4; rt++) acc[rt][ct] = (f32x4){bj, bj, bj, bj};
        }
        const ushort* W1te = W1t + (size_t)e * HH * DD;
        #pragma unroll
        for (int ks = 0; ks < 8; ks++){
            const int kc = ks * 4 + q;       // 16B-chunk index of A fragment
            short8 af[4], bfr[4];
            #pragma unroll
            for (int rt = 0; rt < 4; rt++)
                af[rt] = *(const short8*)&Xs[(rt * 16 + m16) * DD + ((kc ^ swz) * 8)];
            #pragma unroll
            for (int ct = 0; ct < 4; ct++)
                bfr[ct] = *(const short8*)&W1te[(size_t)(c0 + ct * 16 + m16) * DD + ks * 32 + q * 8];
            #pragma unroll
            for (int rt = 0; rt < 4; rt++)
                #pragma unroll
                for (int ct = 0; ct < 4; ct++)
                    acc[rt][ct] = __builtin_amdgcn_mfma_f32_16x16x32_bf16(af[rt], bfr[ct], acc[rt][ct], 0, 0, 0);
        }

        // relu -> bf16 core into this group's LDS buffer
        #pragma unroll
        for (int rt = 0; rt < 4; rt++)
            #pragma unroll
            for (int ct = 0; ct < 4; ct++)
                #pragma unroll
                for (int j = 0; j < 4; j++){
                    const int row = rt * 16 + q * 4 + j;
                    const int col = c0 + ct * 16 + m16;
                    coreSg[row * CS_S + col] = f2bf(fmaxf(acc[rt][ct][j], 0.0f));
                }
        __syncthreads();   // coreS[g] + wES[g] visible to both halves

        // ---- GEMM2: plast_pre = core @ Wp[e] + bp[e] ----
        f32x4 acc2[4][4];
        #pragma unroll
        for (int ct = 0; ct < 4; ct++){
            const float bj = bp[e * HH + c0 + ct * 16 + m16];
            #pragma unroll
            for (int rt = 0; rt < 4; rt++) acc2[rt][ct] = (f32x4){bj, bj, bj, bj};
        }
        const ushort* Wpte = Wpt + (size_t)e * HH * HH;
        #pragma unroll
        for (int ks = 0; ks < 4; ks++){
            const int k0 = ks * 32;
            short8 af[4], bfr[4];
            #pragma unroll
            for (int rt = 0; rt < 4; rt++)
                af[rt] = *(const short8*)&coreSg[(rt * 16 + m16) * CS_S + k0 + q * 8];
            #pragma unroll
            for (int ct = 0; ct < 4; ct++)
                bfr[ct] = *(const short8*)&Wpte[(size_t)(c0 + ct * 16 + m16) * HH + k0 + q * 8];
            #pragma unroll
            for (int rt = 0; rt < 4; rt++)
                #pragma unroll
                for (int ct = 0; ct < 4; ct++)
                    acc2[rt][ct] = __builtin_amdgcn_mfma_f32_16x16x32_bf16(af[rt], bfr[ct], acc2[rt][ct], 0, 0, 0);
        }

        // ---- epilogue partial: red += w_row * (sum_cols + bo[e] on half 0) ----
        const float mv  = mvS[e];
        const float om  = 1.0f - mv;
        const float badd = (half == 0) ? boS[e] : 0.0f;
        float wo[4];
        #pragma unroll
        for (int ct = 0; ct < 4; ct++) wo[ct] = Wo[e * HH + c0 + ct * 16 + m16];

        #pragma unroll
        for (int rt = 0; rt < 4; rt++)
            #pragma unroll
            for (int j = 0; j < 4; j++){
                const int row = rt * 16 + q * 4 + j;
                float s = 0.0f;
                #pragma unroll
                for (int ct = 0; ct < 4; ct++){
                    const int col = c0 + ct * 16 + m16;
                    const float pl = fast_tanh(acc2[rt][ct][j]);
                    const float cv = bf2f(coreSg[row * CS_S + col]);
                    s = fmaf(om * cv + mv * pl, wo[ct], s);
                }
                const float wj = wES[g][row];
                red[rt][j] = fmaf(wj, s + badd, red[rt][j]);
            }
        __syncthreads();   // coreS[g]/wES[g] consumed; safe to overwrite
    }

    // ---- final: reduce over m16, cross-wave sum via redS, single store ----
    #pragma unroll
    for (int off = 8; off >= 1; off >>= 1)
        #pragma unroll
        for (int rt = 0; rt < 4; rt++)
            #pragma unroll
            for (int j = 0; j < 4; j++)
                red[rt][j] += __shfl_xor(red[rt][j], off, 64);

    if (m16 == 0)
        #pragma unroll
        for (int rt = 0; rt < 4; rt++)
            #pragma unroll
            for (int j = 0; j < 4; j++)
                redS[w][rt * 16 + q * 4 + j] = red[rt][j];
    __syncthreads();

    if (t < 64){
        float s = 0.0f;
        #pragma unroll
        for (int ww = 0; ww < 8; ww++) s += redS[ww][t];
        out[rowBase + t] = s;
    }
}

// ---------------------------------------------------------------------------
extern "C" void kernel_launch(void* const* d_in, const int* in_sizes, int n_in,
                              void* d_out, int out_size, void* d_ws, size_t ws_size,
                              hipStream_t stream) {
    (void)in_sizes; (void)n_in; (void)out_size; (void)ws_size;
    const float* x   = (const float*)d_in[0];
    const float* Wg  = (const float*)d_in[1];
    const float* W1  = (const float*)d_in[2];
    const float* b1  = (const float*)d_in[3];
    const float* Wp  = (const float*)d_in[4];
    const float* bp  = (const float*)d_in[5];
    const float* ml  = (const float*)d_in[6];
    const float* Wo  = (const float*)d_in[7];
    const float* bo  = (const float*)d_in[8];
    float* out = (float*)d_out;

    // ws layout (1KB-aligned):
    //   route BB*16 = 256 KB | W1t 512 KB | Wpt 256 KB | xbf 8 MB
    char*   ws    = (char*)d_ws;
    float4* route = (float4*)ws;
    ushort* W1t   = (ushort*)(ws + (size_t)BB * 16);
    ushort* Wpt   = W1t + (size_t)EE * HH * DD;
    ushort* xbf   = Wpt + (size_t)EE * HH * HH;

    // 2 dispatches, no memsets, no atomics anywhere.
    prep_kernel<<<TBLK + RBLK, 256, 0, stream>>>(
        x, Wg, W1, Wp, W1t, Wpt, xbf, route);
    dense_kernel<<<BB / 64, 512, 0, stream>>>(
        xbf, W1t, b1, Wpt, bp, ml, Wo, bo, route, out);
}